// Round 3
// baseline (226.461 us; speedup 1.0000x reference)
//
#include <hip/hip_runtime.h>

typedef unsigned int u32;
typedef __bf16 bf16x8 __attribute__((ext_vector_type(8)));
typedef float f32x4 __attribute__((ext_vector_type(4)));

#define N_TOK 4096   // B*S
#define IN_DIM 2048
#define OUT_DIM 4096
#define NCB 128      // codebooks C
#define NCENT 16     // centroids K
#define VLEN 16      // vec_len V
#define CK 2048      // NCB*NCENT  (GEMM inner dim)

static __device__ __forceinline__ unsigned short f2bf(float f) {
  u32 u = __float_as_uint(f);
  u = (u + 0x7FFFu + ((u >> 16) & 1u)) >> 16;  // round-to-nearest-even
  return (unsigned short)u;
}

// ---------------------------------------------------------------------------
// Kernel 1: Chebyshev argmin -> one-hot bf16 rows of A, fully coalesced.
// Block = 16 tokens x (4 codebook-groups of 16), grid.y splits cg range in 2.
// All global traffic moves through LDS with flat lane-contiguous float4/uint4
// copies: x read = exact 33.5MB full lines, A write = 512B row segments.
// Argmin math identical to the passing R2 kernel (fp32 sub/abs/max, strict <).
// ---------------------------------------------------------------------------
__global__ __launch_bounds__(256) void k_argmin_onehot(
    const float* __restrict__ x,
    const float* __restrict__ cents,
    unsigned short* __restrict__ A) {
  __shared__ float xs[16 * 260];  // 16 tokens x 256 cols, pad->260
  __shared__ float cs[16 * 260];  // 16 codebooks x 256, pad->260
  __shared__ uint4 os[16 * 32];   // 16 tokens x 512B one-hot
  const int tid = threadIdx.x;
  const int n0 = blockIdx.x * 16;
  const int t = tid >> 4;   // token 0..15
  const int cl = tid & 15;  // codebook-local 0..15

  for (int g = 0; g < 4; ++g) {
    const int cg = blockIdx.y * 4 + g;  // 16-codebook group 0..7
    // stage x tile + centroid tile (flat, lane-contiguous)
#pragma unroll
    for (int j = 0; j < 4; ++j) {
      const int idx = tid + 256 * j;   // float4 index 0..1023
      const int row = idx >> 6;        // 64 float4 per row
      const int col = (idx & 63) * 4;
      *(float4*)(xs + row * 260 + col) =
          *(const float4*)(x + (size_t)(n0 + row) * IN_DIM + cg * 256 + col);
      *(float4*)(cs + row * 260 + col) =
          *(const float4*)(cents + ((size_t)cg * 16 + row) * 256 + col);
    }
    __syncthreads();

    float xr[16];
    const float* xv = xs + t * 260 + cl * 16;
#pragma unroll
    for (int q = 0; q < 4; ++q) {
      float4 tv = *(const float4*)(xv + q * 4);
      xr[q * 4 + 0] = tv.x; xr[q * 4 + 1] = tv.y;
      xr[q * 4 + 2] = tv.z; xr[q * 4 + 3] = tv.w;
    }
    const float* cb = cs + cl * 260;
    int bk = 0;
    float bd = 1e30f;
#pragma unroll
    for (int k = 0; k < NCENT; ++k) {
      float d = 0.f;
#pragma unroll
      for (int v = 0; v < VLEN; ++v) d = fmaxf(d, fabsf(xr[v] - cb[k * 16 + v]));
      if (d < bd) { bd = d; bk = k; }  // strict <: first-min == np.argmin
    }
    const u32 wv2 = 0x3F80u << ((bk & 1) * 16);  // bf16(1.0) in the right half
    u32 pk[8];
#pragma unroll
    for (int j = 0; j < 8; ++j) pk[j] = ((bk >> 1) == j) ? wv2 : 0u;
    os[t * 32 + cl * 2]     = make_uint4(pk[0], pk[1], pk[2], pk[3]);
    os[t * 32 + cl * 2 + 1] = make_uint4(pk[4], pk[5], pk[6], pk[7]);
    __syncthreads();

    // write A: 16 rows x 512B contiguous segments, flat lane-contiguous
#pragma unroll
    for (int j = 0; j < 2; ++j) {
      const int idx = tid + 256 * j;  // uint4 index 0..511
      const int row = idx >> 5;       // 32 uint4 per row
      const int col = idx & 31;
      *(uint4*)(A + (size_t)(n0 + row) * CK + cg * 256 + col * 8) =
          os[row * 32 + col];
    }
    __syncthreads();  // protect xs/cs/os before next group
  }
}

// ---------------------------------------------------------------------------
// Kernel 2: lutT[o][c*16+k] = sum_v cents[c,k,v]*w[c*16+v][o], coalesced.
// Block = 64 o-rows x 8 codebooks. w reads 256B/wave contiguous; centroids
// wave-uniform (scalar); bf16 tile staged in LDS; writes = 256B row segments.
// ---------------------------------------------------------------------------
__global__ __launch_bounds__(256) void k_lut(const float* __restrict__ w,
                                             const float* __restrict__ cents,
                                             unsigned short* __restrict__ lutT) {
  __shared__ unsigned short ls[64 * 136];  // 64 o x 128 ck, pad->136
  const int tid = threadIdx.x;
  const int o0 = blockIdx.x * 64;
  const int cg = blockIdx.y;  // 8-codebook group 0..15
  const int p = tid >> 6;     // wave 0..3
  const int ol = tid & 63;

  float acc[2][16];
#pragma unroll
  for (int cc = 0; cc < 2; ++cc)
#pragma unroll
    for (int k = 0; k < 16; ++k) acc[cc][k] = 0.f;

#pragma unroll
  for (int cc = 0; cc < 2; ++cc) {
    const int c = __builtin_amdgcn_readfirstlane(cg * 8 + p * 2 + cc);  // wave-uniform
    const float* cb = cents + (size_t)c * (NCENT * VLEN);               // scalar loads
#pragma unroll
    for (int v = 0; v < VLEN; ++v) {
      const float wv = w[(size_t)(c * 16 + v) * OUT_DIM + o0 + ol];
#pragma unroll
      for (int k = 0; k < NCENT; ++k) acc[cc][k] = fmaf(cb[k * 16 + v], wv, acc[cc][k]);
    }
  }

#pragma unroll
  for (int cc = 0; cc < 2; ++cc) {
    u32* dst = (u32*)(ls + (size_t)ol * 136 + (p * 2 + cc) * 16);
#pragma unroll
    for (int kk = 0; kk < 8; ++kk)
      dst[kk] = (u32)f2bf(acc[cc][2 * kk]) | ((u32)f2bf(acc[cc][2 * kk + 1]) << 16);
  }
  __syncthreads();

  // write 64 rows x 256B contiguous segments, flat lane-contiguous
#pragma unroll
  for (int j = 0; j < 4; ++j) {
    const int idx = tid + 256 * j;  // uint4 index 0..1023
    const int row = idx >> 4;       // 16 uint4 per row
    const int col = idx & 15;
    *(uint4*)(lutT + (size_t)(o0 + row) * CK + cg * 128 + col * 8) =
        *(const uint4*)(ls + row * 136 + col * 8);
  }
}

// ---------------------------------------------------------------------------
// Kernel 3: out[n][o] = sum_ck A[n][ck] * lutT[o][ck] + bias[o]
// m97-recipe bf16 GEMM (unchanged from passing R2 version).
// ---------------------------------------------------------------------------
#define GLD16(g, l)                                                        \
  __builtin_amdgcn_global_load_lds(                                        \
      (const __attribute__((address_space(1))) u32*)(const void*)(g),      \
      (__attribute__((address_space(3))) u32*)(void*)(l), 16, 0, 0)

__global__ __launch_bounds__(256) void k_gemm(
    const unsigned short* __restrict__ A,   // [N_TOK][CK] bf16 bits
    const unsigned short* __restrict__ Bt,  // [OUT_DIM][CK] bf16 bits
    const float* __restrict__ bias,
    float* __restrict__ out) {
  __shared__ unsigned short sA[128 * 32];  // 8KB, row stride 32 (no pad: GLD)
  __shared__ unsigned short sB[128 * 32];  // 8KB
  const int tid = threadIdx.x;
  const int wave = tid >> 6;
  const int lane = tid & 63;
  const int m0 = blockIdx.x * 128;
  const int n0 = blockIdx.y * 128;
  const int wm = (wave >> 1) * 64;
  const int wn = (wave & 1) * 64;

  const int srow = lane >> 2;
  const int scol = (lane & 3) * 8;
  const unsigned short* gA = A + (size_t)(m0 + wave * 32 + srow) * CK + scol;
  const unsigned short* gB = Bt + (size_t)(n0 + wave * 32 + srow) * CK + scol;
  unsigned short* lA = sA + (wave * 32) * 32;
  unsigned short* lB = sB + (wave * 32) * 32;

  const int fr = lane & 15;
  const int fc = (lane >> 4) * 8;

  f32x4 acc[4][4] = {};

  for (int k0 = 0; k0 < CK; k0 += 32) {
    GLD16(gA, lA);
    GLD16(gA + 16 * CK, lA + 16 * 32);
    GLD16(gB, lB);
    GLD16(gB + 16 * CK, lB + 16 * 32);
    gA += 32;
    gB += 32;
    __syncthreads();
    bf16x8 af[4], bfr[4];
#pragma unroll
    for (int i = 0; i < 4; ++i)
      af[i] = *(const bf16x8*)(sA + (wm + i * 16 + fr) * 32 + fc);
#pragma unroll
    for (int j = 0; j < 4; ++j)
      bfr[j] = *(const bf16x8*)(sB + (wn + j * 16 + fr) * 32 + fc);
#pragma unroll
    for (int i = 0; i < 4; ++i)
#pragma unroll
      for (int j = 0; j < 4; ++j)
        acc[i][j] =
            __builtin_amdgcn_mfma_f32_16x16x32_bf16(af[i], bfr[j], acc[i][j], 0, 0, 0);
    __syncthreads();
  }

  const int col = lane & 15;
  const int rb = (lane >> 4) * 4;
  float bj[4];
#pragma unroll
  for (int j = 0; j < 4; ++j) bj[j] = bias[n0 + wn + j * 16 + col];
#pragma unroll
  for (int i = 0; i < 4; ++i) {
    const int gm = m0 + wm + i * 16 + rb;
#pragma unroll
    for (int j = 0; j < 4; ++j) {
      const int gn = n0 + wn + j * 16 + col;
      float* op = out + (size_t)gm * OUT_DIM + gn;
#pragma unroll
      for (int r = 0; r < 4; ++r) op[(size_t)r * OUT_DIM] = acc[i][j][r] + bj[j];
    }
  }
}

// ---------------------------------------------------------------------------
extern "C" void kernel_launch(void* const* d_in, const int* in_sizes, int n_in,
                              void* d_out, int out_size, void* d_ws, size_t ws_size,
                              hipStream_t stream) {
  (void)in_sizes; (void)n_in; (void)out_size; (void)ws_size;
  const float* x      = (const float*)d_in[0];
  const float* weight = (const float*)d_in[1];
  const float* cents  = (const float*)d_in[2];
  const float* bias   = (const float*)d_in[3];
  // d_in[4] = vec_len (16), hardcoded

  unsigned short* A    = (unsigned short*)d_ws;   // [4096][2048] bf16 = 16.8MB
  unsigned short* lutT = A + (size_t)N_TOK * CK;  // [4096][2048] bf16 = 16.8MB
  float* out = (float*)d_out;

  k_argmin_onehot<<<dim3(N_TOK / 16, 2), 256, 0, stream>>>(x, cents, A);
  k_lut<<<dim3(OUT_DIM / 64, NCB / 8), 256, 0, stream>>>(weight, cents, lutT);
  k_gemm<<<dim3(N_TOK / 128, OUT_DIM / 128), 256, 0, stream>>>(A, lutT, bias, out);
}

// Round 4
// 222.620 us; speedup vs baseline: 1.0173x; 1.0173x over previous
//
#include <hip/hip_runtime.h>

typedef unsigned int u32;
typedef __bf16 bf16x8 __attribute__((ext_vector_type(8)));
typedef float f32x4 __attribute__((ext_vector_type(4)));

#define N_TOK 4096   // B*S
#define IN_DIM 2048
#define OUT_DIM 4096
#define NCB 128      // codebooks C
#define NCENT 16     // centroids K
#define VLEN 16      // vec_len V
#define CK 2048      // NCB*NCENT  (GEMM inner dim)
#define AST 40       // sA row stride in shorts: 80B = 16B-aligned, bank-spread

static __device__ __forceinline__ unsigned short f2bf(float f) {
  u32 u = __float_as_uint(f);
  u = (u + 0x7FFFu + ((u >> 16) & 1u)) >> 16;  // round-to-nearest-even
  return (unsigned short)u;
}

// ---------------------------------------------------------------------------
// Kernel 1: Chebyshev argmin -> u8 index per (token, codebook).  512KB output
// instead of a 16.8MB one-hot matrix.  Math identical to the passing R2/R3
// kernels: fp32 sub/abs/max, strict < ascending k == np.argmin tie-break.
// Block = 16 tokens x (4 codebook-groups of 16); grid.y splits cg range in 2.
// ---------------------------------------------------------------------------
__global__ __launch_bounds__(256) void k_argmin_idx(
    const float* __restrict__ x,
    const float* __restrict__ cents,
    unsigned char* __restrict__ idx) {
  __shared__ float xs[16 * 260];  // 16 tokens x 256 cols, pad->260
  __shared__ float cs[16 * 260];  // 16 codebooks x 256, pad->260
  const int tid = threadIdx.x;
  const int n0 = blockIdx.x * 16;
  const int t = tid >> 4;   // token 0..15
  const int cl = tid & 15;  // codebook-local 0..15

  for (int g = 0; g < 4; ++g) {
    const int cg = blockIdx.y * 4 + g;  // 16-codebook group 0..7
#pragma unroll
    for (int j = 0; j < 4; ++j) {
      const int fi = tid + 256 * j;   // float4 index 0..1023
      const int row = fi >> 6;        // 64 float4 per row
      const int col = (fi & 63) * 4;
      *(float4*)(xs + row * 260 + col) =
          *(const float4*)(x + (size_t)(n0 + row) * IN_DIM + cg * 256 + col);
      *(float4*)(cs + row * 260 + col) =
          *(const float4*)(cents + ((size_t)cg * 16 + row) * 256 + col);
    }
    __syncthreads();

    float xr[16];
    const float* xv = xs + t * 260 + cl * 16;
#pragma unroll
    for (int q = 0; q < 4; ++q) {
      float4 tv = *(const float4*)(xv + q * 4);
      xr[q * 4 + 0] = tv.x; xr[q * 4 + 1] = tv.y;
      xr[q * 4 + 2] = tv.z; xr[q * 4 + 3] = tv.w;
    }
    const float* cb = cs + cl * 260;
    int bk = 0;
    float bd = 1e30f;
#pragma unroll
    for (int k = 0; k < NCENT; ++k) {
      float d = 0.f;
#pragma unroll
      for (int v = 0; v < VLEN; ++v) d = fmaxf(d, fabsf(xr[v] - cb[k * 16 + v]));
      if (d < bd) { bd = d; bk = k; }  // strict <: first-min == np.argmin
    }
    idx[(size_t)(n0 + t) * NCB + cg * 16 + cl] = (unsigned char)bk;
    __syncthreads();  // protect xs/cs before next group
  }
}

// ---------------------------------------------------------------------------
// Kernel 2: lutT[o][c*16+k] = sum_v cents[c,k,v]*w[c*16+v][o]  (unchanged R3)
// ---------------------------------------------------------------------------
__global__ __launch_bounds__(256) void k_lut(const float* __restrict__ w,
                                             const float* __restrict__ cents,
                                             unsigned short* __restrict__ lutT) {
  __shared__ unsigned short ls[64 * 136];  // 64 o x 128 ck, pad->136
  const int tid = threadIdx.x;
  const int o0 = blockIdx.x * 64;
  const int cg = blockIdx.y;  // 8-codebook group 0..15
  const int p = tid >> 6;     // wave 0..3
  const int ol = tid & 63;

  float acc[2][16];
#pragma unroll
  for (int cc = 0; cc < 2; ++cc)
#pragma unroll
    for (int k = 0; k < 16; ++k) acc[cc][k] = 0.f;

#pragma unroll
  for (int cc = 0; cc < 2; ++cc) {
    const int c = __builtin_amdgcn_readfirstlane(cg * 8 + p * 2 + cc);
    const float* cb = cents + (size_t)c * (NCENT * VLEN);  // scalar loads
#pragma unroll
    for (int v = 0; v < VLEN; ++v) {
      const float wv = w[(size_t)(c * 16 + v) * OUT_DIM + o0 + ol];
#pragma unroll
      for (int k = 0; k < NCENT; ++k) acc[cc][k] = fmaf(cb[k * 16 + v], wv, acc[cc][k]);
    }
  }

#pragma unroll
  for (int cc = 0; cc < 2; ++cc) {
    u32* dst = (u32*)(ls + (size_t)ol * 136 + (p * 2 + cc) * 16);
#pragma unroll
    for (int kk = 0; kk < 8; ++kk)
      dst[kk] = (u32)f2bf(acc[cc][2 * kk]) | ((u32)f2bf(acc[cc][2 * kk + 1]) << 16);
  }
  __syncthreads();

#pragma unroll
  for (int j = 0; j < 4; ++j) {
    const int fi = tid + 256 * j;  // uint4 index 0..1023
    const int row = fi >> 4;       // 16 uint4 per row
    const int col = fi & 15;
    *(uint4*)(lutT + (size_t)(o0 + row) * CK + cg * 128 + col * 8) =
        *(const uint4*)(ls + row * 136 + col * 8);
  }
}

// ---------------------------------------------------------------------------
// Kernel 3: fused one-hot GEMM.  out[n][o] = lutT[o][c*16+idx[n][c]] summed
// over c, + bias.  A-tile is never in HBM: u8 indices staged to LDS once per
// block; per K-step each thread owns one (token, codebook) slot of the padded
// LDS A-tile and does clear-prev/set-new ds_write_b16 (slot ownership is
// disjoint; the existing two barriers order build vs MFMA reads).
// B staged via global_load_lds width=16 as before.
// ---------------------------------------------------------------------------
#define GLD16(g, l)                                                        \
  __builtin_amdgcn_global_load_lds(                                        \
      (const __attribute__((address_space(1))) u32*)(const void*)(g),      \
      (__attribute__((address_space(3))) u32*)(void*)(l), 16, 0, 0)

__global__ __launch_bounds__(256) void k_gemm(
    const unsigned char* __restrict__ idx,  // [N_TOK][NCB] u8
    const unsigned short* __restrict__ Bt,  // [OUT_DIM][CK] bf16 bits
    const float* __restrict__ bias,
    float* __restrict__ out) {
  __shared__ unsigned short sA[128 * AST];   // one-hot tile, built in LDS
  __shared__ unsigned short sB[128 * 32];    // 8KB, stride 32 (GLD16: no pad)
  __shared__ unsigned char sIdx[128 * 132];  // token x codebook, pad 132
  const int tid = threadIdx.x;
  const int wave = tid >> 6;
  const int lane = tid & 63;
  const int m0 = blockIdx.x * 128;
  const int n0 = blockIdx.y * 128;
  const int wm = (wave >> 1) * 64;
  const int wn = (wave & 1) * 64;

  // ---- stage sIdx: 16KB, fully coalesced ----
#pragma unroll
  for (int j = 0; j < 4; ++j) {
    const int off = tid + 256 * j;   // uint4 index 0..1023
    const int row = off >> 3;        // 8 x 16B per 128B row
    const int col = (off & 7) * 16;
    *(uint4*)(sIdx + row * 132 + col) =
        *(const uint4*)(idx + (size_t)(m0 + row) * NCB + col);
  }

  // ---- zero own sA segment (cols 0..31 of one row-half each) ----
  const int brow = tid >> 1;  // builder row 0..127
  const int bch = tid & 1;    // builder codebook-half 0..1
  {
    uint4 z = make_uint4(0, 0, 0, 0);
    uint4* zp = (uint4*)(sA + brow * AST + bch * 16);
    zp[0] = z; zp[1] = z;
  }
  __syncthreads();  // sIdx + zeroed sA visible to all

  // ---- B staging pointers (unchanged m97 pattern) ----
  const int srow = lane >> 2;
  const int scol = (lane & 3) * 8;
  const unsigned short* gB = Bt + (size_t)(n0 + wave * 32 + srow) * CK + scol;
  unsigned short* lB = sB + (wave * 32) * 32;

  const int fr = lane & 15;        // fragment row (m or n)
  const int fc = (lane >> 4) * 8;  // fragment k offset

  f32x4 acc[4][4] = {};

  unsigned prevpos = brow * AST + bch * 16;  // iter-0 clear hits a zero slot
  const unsigned char* ip = sIdx + brow * 132 + bch;  // advances 2/iter

  for (int k0 = 0; k0 < CK; k0 += 32) {
    // build A-tile slot: clear previous one-hot, set new (same-lane ordered)
    const unsigned kb = *ip;
    ip += 2;
    sA[prevpos] = 0;
    prevpos = brow * AST + bch * 16 + kb;
    sA[prevpos] = 0x3F80;  // bf16(1.0)

    GLD16(gB, lB);
    GLD16(gB + 16 * CK, lB + 16 * 32);
    gB += 32;
    __syncthreads();  // drains vmem (B) + LDS builds

    bf16x8 af[4], bfr[4];
#pragma unroll
    for (int i = 0; i < 4; ++i)
      af[i] = *(const bf16x8*)(sA + (wm + i * 16 + fr) * AST + fc);
#pragma unroll
    for (int j = 0; j < 4; ++j)
      bfr[j] = *(const bf16x8*)(sB + (wn + j * 16 + fr) * 32 + fc);
#pragma unroll
    for (int i = 0; i < 4; ++i)
#pragma unroll
      for (int j = 0; j < 4; ++j)
        acc[i][j] =
            __builtin_amdgcn_mfma_f32_16x16x32_bf16(af[i], bfr[j], acc[i][j], 0, 0, 0);
    __syncthreads();  // MFMA reads done before next build/overwrite
  }

  // epilogue: D layout col=lane&15, row=(lane>>4)*4+r  [m89-verified]
  const int col = lane & 15;
  const int rb = (lane >> 4) * 4;
  float bj[4];
#pragma unroll
  for (int j = 0; j < 4; ++j) bj[j] = bias[n0 + wn + j * 16 + col];
#pragma unroll
  for (int i = 0; i < 4; ++i) {
    const int gm = m0 + wm + i * 16 + rb;
#pragma unroll
    for (int j = 0; j < 4; ++j) {
      const int gn = n0 + wn + j * 16 + col;
      float* op = out + (size_t)gm * OUT_DIM + gn;
#pragma unroll
      for (int r = 0; r < 4; ++r) op[(size_t)r * OUT_DIM] = acc[i][j][r] + bj[j];
    }
  }
}

// ---------------------------------------------------------------------------
extern "C" void kernel_launch(void* const* d_in, const int* in_sizes, int n_in,
                              void* d_out, int out_size, void* d_ws, size_t ws_size,
                              hipStream_t stream) {
  (void)in_sizes; (void)n_in; (void)out_size; (void)ws_size;
  const float* x      = (const float*)d_in[0];
  const float* weight = (const float*)d_in[1];
  const float* cents  = (const float*)d_in[2];
  const float* bias   = (const float*)d_in[3];
  // d_in[4] = vec_len (16), hardcoded

  unsigned short* lutT = (unsigned short*)d_ws;               // 16.8MB
  unsigned char* idx   = (unsigned char*)d_ws + (size_t)OUT_DIM * CK * 2;  // 512KB
  float* out = (float*)d_out;

  k_argmin_idx<<<dim3(N_TOK / 16, 2), 256, 0, stream>>>(x, cents, idx);
  k_lut<<<dim3(OUT_DIM / 64, NCB / 8), 256, 0, stream>>>(weight, cents, lutT);
  k_gemm<<<dim3(N_TOK / 128, OUT_DIM / 128), 256, 0, stream>>>(idx, lutT, bias, out);
}

// Round 5
// 197.288 us; speedup vs baseline: 1.1479x; 1.1284x over previous
//
#include <hip/hip_runtime.h>

typedef unsigned int u32;
typedef __bf16 bf16x8 __attribute__((ext_vector_type(8)));
typedef float f32x4 __attribute__((ext_vector_type(4)));

#define N_TOK 4096   // B*S
#define IN_DIM 2048
#define OUT_DIM 4096
#define NCB 128      // codebooks C
#define NCENT 16     // centroids K
#define VLEN 16      // vec_len V
#define CK 2048      // NCB*NCENT  (GEMM inner dim)
#define AST 40       // sA row stride in shorts: 80B, 16B-aligned, 2-way banks
#define KB 64        // K-blocks (CK/32)

static __device__ __forceinline__ unsigned short f2bf(float f) {
  u32 u = __float_as_uint(f);
  u = (u + 0x7FFFu + ((u >> 16) & 1u)) >> 16;  // round-to-nearest-even
  return (unsigned short)u;
}

// ---------------------------------------------------------------------------
// Kernel 1: Chebyshev argmin -> u8 index per (token, codebook).  (unchanged)
// fp32 sub/abs/max, strict < ascending k == np.argmin tie-break.
// ---------------------------------------------------------------------------
__global__ __launch_bounds__(256) void k_argmin_idx(
    const float* __restrict__ x,
    const float* __restrict__ cents,
    unsigned char* __restrict__ idx) {
  __shared__ float xs[16 * 260];
  __shared__ float cs[16 * 260];
  const int tid = threadIdx.x;
  const int n0 = blockIdx.x * 16;
  const int t = tid >> 4;
  const int cl = tid & 15;

  for (int g = 0; g < 4; ++g) {
    const int cg = blockIdx.y * 4 + g;
#pragma unroll
    for (int j = 0; j < 4; ++j) {
      const int fi = tid + 256 * j;
      const int row = fi >> 6;
      const int col = (fi & 63) * 4;
      *(float4*)(xs + row * 260 + col) =
          *(const float4*)(x + (size_t)(n0 + row) * IN_DIM + cg * 256 + col);
      *(float4*)(cs + row * 260 + col) =
          *(const float4*)(cents + ((size_t)cg * 16 + row) * 256 + col);
    }
    __syncthreads();

    float xr[16];
    const float* xv = xs + t * 260 + cl * 16;
#pragma unroll
    for (int q = 0; q < 4; ++q) {
      float4 tv = *(const float4*)(xv + q * 4);
      xr[q * 4 + 0] = tv.x; xr[q * 4 + 1] = tv.y;
      xr[q * 4 + 2] = tv.z; xr[q * 4 + 3] = tv.w;
    }
    const float* cb = cs + cl * 260;
    int bk = 0;
    float bd = 1e30f;
#pragma unroll
    for (int k = 0; k < NCENT; ++k) {
      float d = 0.f;
#pragma unroll
      for (int v = 0; v < VLEN; ++v) d = fmaxf(d, fabsf(xr[v] - cb[k * 16 + v]));
      if (d < bd) { bd = d; bk = k; }
    }
    idx[(size_t)(n0 + t) * NCB + cg * 16 + cl] = (unsigned char)bk;
    __syncthreads();
  }
}

// ---------------------------------------------------------------------------
// Kernel 2: LUT in MFMA B-FRAGMENT order.  For n-tile tn=o>>4, k-block
// kb=ck>>5, the 16x32 tile is 1KB contiguous: lane l (= (o&15) + ((ck&31)>>3
// *16)) holds 8 bf16 (ck&7).  GEMM waves then load B-frags with plain
// coalesced dwordx4 straight to registers — no LDS for B at all.
// ---------------------------------------------------------------------------
__global__ __launch_bounds__(256) void k_lut(const float* __restrict__ w,
                                             const float* __restrict__ cents,
                                             char* __restrict__ lutF) {
  const int tid = threadIdx.x;
  const int o0 = blockIdx.x * 64;
  const int cg = blockIdx.y;  // 8-codebook group 0..15
  const int p = tid >> 6;     // wave 0..3
  const int ol = tid & 63;
  const int o = o0 + ol;

  float acc[2][16];
#pragma unroll
  for (int cc = 0; cc < 2; ++cc)
#pragma unroll
    for (int k = 0; k < 16; ++k) acc[cc][k] = 0.f;

#pragma unroll
  for (int cc = 0; cc < 2; ++cc) {
    const int c = __builtin_amdgcn_readfirstlane(cg * 8 + p * 2 + cc);
    const float* cb = cents + (size_t)c * (NCENT * VLEN);  // scalar loads
#pragma unroll
    for (int v = 0; v < VLEN; ++v) {
      const float wv = w[(size_t)(c * 16 + v) * OUT_DIM + o];
#pragma unroll
      for (int k = 0; k < NCENT; ++k) acc[cc][k] = fmaf(cb[k * 16 + v], wv, acc[cc][k]);
    }
  }

#pragma unroll
  for (int cc = 0; cc < 2; ++cc) {
    const int c = cg * 8 + p * 2 + cc;
    u32 g[8];
#pragma unroll
    for (int kk = 0; kk < 8; ++kk)
      g[kk] = (u32)f2bf(acc[cc][2 * kk]) | ((u32)f2bf(acc[cc][2 * kk + 1]) << 16);
    char* base = lutF + ((size_t)(o >> 4) * KB + (c >> 1)) * 1024;
    const int l0 = (o & 15) + ((c & 1) * 2) * 16;  // k=0..7 chunk
    *(uint4*)(base + l0 * 16)        = make_uint4(g[0], g[1], g[2], g[3]);
    *(uint4*)(base + (l0 + 16) * 16) = make_uint4(g[4], g[5], g[6], g[7]);
  }
}

// ---------------------------------------------------------------------------
// Kernel 3: fused one-hot GEMM, B in registers.
// A one-hot built in DOUBLE-BUFFERED LDS (one barrier/iter); B(k+1) frags
// loaded at iter top (coalesced dwordx4, covered by builds+ds_reads+MFMA
// before the barrier drain); MFMA uses B(k) loaded last iter (drained by the
// previous barrier -> no wait).
// ---------------------------------------------------------------------------
__global__ __launch_bounds__(256) void k_gemm(
    const unsigned char* __restrict__ idx,  // [N_TOK][NCB] u8
    const char* __restrict__ Bf,            // fragment-ordered LUT
    const float* __restrict__ bias,
    float* __restrict__ out) {
  __shared__ unsigned short sA[2 * 128 * AST];  // 20.5KB double-buffered
  __shared__ unsigned char sIdx[128 * 132];     // 16.9KB, pad 132 vs banks
  const int tid = threadIdx.x;
  const int wave = tid >> 6;
  const int lane = tid & 63;
  const int m0 = blockIdx.x * 128;
  const int n0 = blockIdx.y * 128;
  const int wm = (wave >> 1) * 64;
  const int wn = (wave & 1) * 64;

  // ---- stage sIdx (16KB, coalesced) ----
#pragma unroll
  for (int j = 0; j < 4; ++j) {
    const int off = tid + 256 * j;
    const int row = off >> 3;
    const int col = (off & 7) * 16;
    *(uint4*)(sIdx + row * 132 + col) =
        *(const uint4*)(idx + (size_t)(m0 + row) * NCB + col);
  }
  // ---- zero both sA buffers: 20480B = 1280 uint4, 5/thread ----
  {
    uint4 z = make_uint4(0, 0, 0, 0);
    uint4* zp = (uint4*)sA;
#pragma unroll
    for (int i = 0; i < 5; ++i) zp[tid + 256 * i] = z;
  }
  const int brow = tid >> 1;  // builder row 0..127
  const int bch = tid & 1;    // builder codebook-half
  const int slotbase = brow * AST + bch * 16;
  int prev0 = slotbase;              // buf0 slot (zeroed -> clear harmless)
  int prev1 = 128 * AST + slotbase;  // buf1 slot
  __syncthreads();  // sIdx + zeros visible

  // build iter-0 one-hot into buf0
  {
    const unsigned kb = sIdx[brow * 132 + bch];
    sA[prev0] = 0;
    prev0 = slotbase + kb;
    sA[prev0] = 0x3F80;  // bf16(1.0)
  }

  // B-frag pointers: tile row base for this wave's n-range
  const int tb = (n0 >> 4) + (wn >> 4);
  const char* bbase = Bf + (size_t)lane * 16;
  uint4 Bc[4], Bn[4];
#pragma unroll
  for (int j = 0; j < 4; ++j)
    Bc[j] = *(const uint4*)(bbase + ((size_t)(tb + j) * KB + 0) * 1024);
  __syncthreads();  // buf0 build visible; B iter-0 drained

  const int fr = lane & 15;
  const int fc = (lane >> 4) * 8;
  const unsigned short* sA0 = sA;
  const unsigned short* sA1 = sA + 128 * AST;

  f32x4 acc[4][4] = {};

  for (int t = 0; t < KB; t += 2) {
    // ---- iter t (even): frags from buf0, MFMA with Bc; build buf1; load Bn
    {
      const int tn = t + 1;  // <= 63
#pragma unroll
      for (int j = 0; j < 4; ++j)
        Bn[j] = *(const uint4*)(bbase + ((size_t)(tb + j) * KB + tn) * 1024);
      const unsigned kb = sIdx[brow * 132 + 2 * tn + bch];
      sA[prev1] = 0;
      prev1 = 128 * AST + slotbase + kb;
      sA[prev1] = 0x3F80;
      bf16x8 af[4];
#pragma unroll
      for (int i = 0; i < 4; ++i)
        af[i] = *(const bf16x8*)(sA0 + (wm + i * 16 + fr) * AST + fc);
#pragma unroll
      for (int i = 0; i < 4; ++i)
#pragma unroll
        for (int j = 0; j < 4; ++j)
          acc[i][j] = __builtin_amdgcn_mfma_f32_16x16x32_bf16(
              af[i], *(const bf16x8*)&Bc[j], acc[i][j], 0, 0, 0);
      __syncthreads();
    }
    // ---- iter t+1 (odd): frags from buf1, MFMA with Bn; build buf0; load Bc
    {
      const int tn = (t + 2 < KB) ? t + 2 : KB - 1;  // clamp; buf0 dead at end
#pragma unroll
      for (int j = 0; j < 4; ++j)
        Bc[j] = *(const uint4*)(bbase + ((size_t)(tb + j) * KB + tn) * 1024);
      const unsigned kb = sIdx[brow * 132 + 2 * tn + bch];
      sA[prev0] = 0;
      prev0 = slotbase + kb;
      sA[prev0] = 0x3F80;
      bf16x8 af[4];
#pragma unroll
      for (int i = 0; i < 4; ++i)
        af[i] = *(const bf16x8*)(sA1 + (wm + i * 16 + fr) * AST + fc);
#pragma unroll
      for (int i = 0; i < 4; ++i)
#pragma unroll
        for (int j = 0; j < 4; ++j)
          acc[i][j] = __builtin_amdgcn_mfma_f32_16x16x32_bf16(
              af[i], *(const bf16x8*)&Bn[j], acc[i][j], 0, 0, 0);
      __syncthreads();
    }
  }

  // epilogue: D layout col=lane&15, row=(lane>>4)*4+r  [m89-verified]
  const int col = lane & 15;
  const int rb = (lane >> 4) * 4;
  float bj[4];
#pragma unroll
  for (int j = 0; j < 4; ++j) bj[j] = bias[n0 + wn + j * 16 + col];
#pragma unroll
  for (int i = 0; i < 4; ++i) {
    const int gm = m0 + wm + i * 16 + rb;
#pragma unroll
    for (int j = 0; j < 4; ++j) {
      const int gn = n0 + wn + j * 16 + col;
      float* op = out + (size_t)gm * OUT_DIM + gn;
#pragma unroll
      for (int r = 0; r < 4; ++r) op[(size_t)r * OUT_DIM] = acc[i][j][r] + bj[j];
    }
  }
}

// ---------------------------------------------------------------------------
extern "C" void kernel_launch(void* const* d_in, const int* in_sizes, int n_in,
                              void* d_out, int out_size, void* d_ws, size_t ws_size,
                              hipStream_t stream) {
  (void)in_sizes; (void)n_in; (void)out_size; (void)ws_size;
  const float* x      = (const float*)d_in[0];
  const float* weight = (const float*)d_in[1];
  const float* cents  = (const float*)d_in[2];
  const float* bias   = (const float*)d_in[3];
  // d_in[4] = vec_len (16), hardcoded

  char* lutF = (char*)d_ws;                              // 16.8MB frag-order
  unsigned char* idx = (unsigned char*)d_ws + (size_t)OUT_DIM * CK * 2;  // 512KB
  float* out = (float*)d_out;

  k_argmin_idx<<<dim3(N_TOK / 16, 2), 256, 0, stream>>>(x, cents, idx);
  k_lut<<<dim3(OUT_DIM / 64, NCB / 8), 256, 0, stream>>>(weight, cents, lutF);
  k_gemm<<<dim3(N_TOK / 128, OUT_DIM / 128), 256, 0, stream>>>(idx, lutF, bias, out);
}

// Round 6
// 194.092 us; speedup vs baseline: 1.1668x; 1.0165x over previous
//
#include <hip/hip_runtime.h>

typedef unsigned int u32;
typedef __bf16 bf16x8 __attribute__((ext_vector_type(8)));
typedef float f32x4 __attribute__((ext_vector_type(4)));

#define N_TOK 4096   // B*S
#define IN_DIM 2048
#define OUT_DIM 4096
#define NCB 128      // codebooks C
#define NCENT 16     // centroids K
#define VLEN 16      // vec_len V
#define CK 2048      // NCB*NCENT  (GEMM inner dim)
#define KB 64        // K-blocks (CK/32)

static __device__ __forceinline__ unsigned short f2bf(float f) {
  u32 u = __float_as_uint(f);
  u = (u + 0x7FFFu + ((u >> 16) & 1u)) >> 16;  // round-to-nearest-even
  return (unsigned short)u;
}

// ---------------------------------------------------------------------------
// Kernel 1: Chebyshev argmin -> u8 index per (token, codebook).  (unchanged)
// fp32 sub/abs/max, strict < ascending k == np.argmin tie-break.
// ---------------------------------------------------------------------------
__global__ __launch_bounds__(256) void k_argmin_idx(
    const float* __restrict__ x,
    const float* __restrict__ cents,
    unsigned char* __restrict__ idx) {
  __shared__ float xs[16 * 260];
  __shared__ float cs[16 * 260];
  const int tid = threadIdx.x;
  const int n0 = blockIdx.x * 16;
  const int t = tid >> 4;
  const int cl = tid & 15;

  for (int g = 0; g < 4; ++g) {
    const int cg = blockIdx.y * 4 + g;
#pragma unroll
    for (int j = 0; j < 4; ++j) {
      const int fi = tid + 256 * j;
      const int row = fi >> 6;
      const int col = (fi & 63) * 4;
      *(float4*)(xs + row * 260 + col) =
          *(const float4*)(x + (size_t)(n0 + row) * IN_DIM + cg * 256 + col);
      *(float4*)(cs + row * 260 + col) =
          *(const float4*)(cents + ((size_t)cg * 16 + row) * 256 + col);
    }
    __syncthreads();

    float xr[16];
    const float* xv = xs + t * 260 + cl * 16;
#pragma unroll
    for (int q = 0; q < 4; ++q) {
      float4 tv = *(const float4*)(xv + q * 4);
      xr[q * 4 + 0] = tv.x; xr[q * 4 + 1] = tv.y;
      xr[q * 4 + 2] = tv.z; xr[q * 4 + 3] = tv.w;
    }
    const float* cb = cs + cl * 260;
    int bk = 0;
    float bd = 1e30f;
#pragma unroll
    for (int k = 0; k < NCENT; ++k) {
      float d = 0.f;
#pragma unroll
      for (int v = 0; v < VLEN; ++v) d = fmaxf(d, fabsf(xr[v] - cb[k * 16 + v]));
      if (d < bd) { bd = d; bk = k; }
    }
    idx[(size_t)(n0 + t) * NCB + cg * 16 + cl] = (unsigned char)bk;
    __syncthreads();
  }
}

// ---------------------------------------------------------------------------
// Kernel 2: LUT in MFMA B-fragment order (unchanged from passing R5).
// Tile (tn=o>>4, kb=ck>>5) is 1KB contiguous; lane l = (o&15)+((ck&31)>>3)*16
// holds 8 bf16.
// ---------------------------------------------------------------------------
__global__ __launch_bounds__(256) void k_lut(const float* __restrict__ w,
                                             const float* __restrict__ cents,
                                             char* __restrict__ lutF) {
  const int tid = threadIdx.x;
  const int o0 = blockIdx.x * 64;
  const int cg = blockIdx.y;  // 8-codebook group 0..15
  const int p = tid >> 6;     // wave 0..3
  const int ol = tid & 63;
  const int o = o0 + ol;

  float acc[2][16];
#pragma unroll
  for (int cc = 0; cc < 2; ++cc)
#pragma unroll
    for (int k = 0; k < 16; ++k) acc[cc][k] = 0.f;

#pragma unroll
  for (int cc = 0; cc < 2; ++cc) {
    const int c = __builtin_amdgcn_readfirstlane(cg * 8 + p * 2 + cc);
    const float* cb = cents + (size_t)c * (NCENT * VLEN);  // scalar loads
#pragma unroll
    for (int v = 0; v < VLEN; ++v) {
      const float wv = w[(size_t)(c * 16 + v) * OUT_DIM + o];
#pragma unroll
      for (int k = 0; k < NCENT; ++k) acc[cc][k] = fmaf(cb[k * 16 + v], wv, acc[cc][k]);
    }
  }

#pragma unroll
  for (int cc = 0; cc < 2; ++cc) {
    const int c = cg * 8 + p * 2 + cc;
    u32 g[8];
#pragma unroll
    for (int kk = 0; kk < 8; ++kk)
      g[kk] = (u32)f2bf(acc[cc][2 * kk]) | ((u32)f2bf(acc[cc][2 * kk + 1]) << 16);
    char* base = lutF + ((size_t)(o >> 4) * KB + (c >> 1)) * 1024;
    const int l0 = (o & 15) + ((c & 1) * 2) * 16;
    *(uint4*)(base + l0 * 16)        = make_uint4(g[0], g[1], g[2], g[3]);
    *(uint4*)(base + (l0 + 16) * 16) = make_uint4(g[4], g[5], g[6], g[7]);
  }
}

// ---------------------------------------------------------------------------
// Kernel 3: fused one-hot GEMM.  A one-hot built in FRAGMENT-ORDER LDS
// (double-buffered, 2 x 8KB): per k-block, 8 m-tiles of 1KB; element (m,kl)
// at short-index mtile*512 + m*8 + (kl>>3)*128 + (kl&7), so each wave's
// 4 ds_read_b128 are lane-sequential (zero conflicts, imm offsets).
// B-frags in registers from frag-ordered lutF (layout validated by R5 pass).
// Builder (brow,bch) owns shorts {slotbase+0..7, slotbase+128..135}: the
// clear-prev/set-new pair stays within its own slots (kb masked to 4 bits).
// ---------------------------------------------------------------------------
__global__ __launch_bounds__(256) void k_gemm(
    const unsigned char* __restrict__ idx,  // [N_TOK][NCB] u8
    const char* __restrict__ Bf,            // fragment-ordered LUT
    const float* __restrict__ bias,
    float* __restrict__ out) {
  __shared__ unsigned short sA[2 * 4096];    // 2 bufs x 8KB, fragment order
  __shared__ unsigned char sIdx[128 * 132];  // 16.9KB, pad 132
  const int tid = threadIdx.x;
  const int wave = tid >> 6;
  const int lane = tid & 63;
  const int m0 = blockIdx.x * 128;
  const int n0 = blockIdx.y * 128;
  const int wm = (wave >> 1) * 64;
  const int wn = (wave & 1) * 64;

  // ---- stage sIdx (16KB, coalesced) ----
#pragma unroll
  for (int j = 0; j < 4; ++j) {
    const int off = tid + 256 * j;
    const int row = off >> 3;
    const int col = (off & 7) * 16;
    *(uint4*)(sIdx + row * 132 + col) =
        *(const uint4*)(idx + (size_t)(m0 + row) * NCB + col);
  }
  // ---- zero both sA buffers: 16KB = 1024 uint4, 4/thread ----
  {
    uint4 z = make_uint4(0, 0, 0, 0);
    uint4* zp = (uint4*)sA;
#pragma unroll
    for (int i = 0; i < 4; ++i) zp[tid + 256 * i] = z;
  }
  const int brow = tid >> 1;  // builder token-row 0..127
  const int bch = tid & 1;    // builder codebook-half
  // slotbase: mtile*512 + m*8 + bch*256  (short index, buf0)
  const int slotbase = (brow >> 4) * 512 + (brow & 15) * 8 + bch * 256;
  const unsigned char* iprow = sIdx + brow * 132 + bch;
  int prev0 = slotbase;         // zeroed -> first clear harmless
  int prev1 = 4096 + slotbase;  // buf1
  __syncthreads();  // sIdx + zeros visible

  // build iter-0 one-hot into buf0
  {
    const int kb = iprow[0] & 15;
    sA[prev0] = 0;
    prev0 = slotbase + (((kb & 8) << 4) | (kb & 7));
    sA[prev0] = 0x3F80;  // bf16(1.0)
  }

  // B-frag offsets: 32-bit, SGPR-base addressing; +=1024 per k-block
  const int tb = (n0 >> 4) + (wn >> 4);
  u32 bo0 = (u32)(tb + 0) * (KB * 1024) + (u32)lane * 16;
  u32 bo1 = bo0 + KB * 1024;
  u32 bo2 = bo1 + KB * 1024;
  u32 bo3 = bo2 + KB * 1024;
  uint4 Bc[4], Bn[4];
  Bc[0] = *(const uint4*)(Bf + bo0);
  Bc[1] = *(const uint4*)(Bf + bo1);
  Bc[2] = *(const uint4*)(Bf + bo2);
  Bc[3] = *(const uint4*)(Bf + bo3);
  bo0 += 1024; bo1 += 1024; bo2 += 1024; bo3 += 1024;
  __syncthreads();  // buf0 build visible

  // per-wave fragment base pointers (imm offsets i*1024B in ds_read)
  const unsigned short* pA0 = sA + (wave >> 1) * 2048 + lane * 8;
  const unsigned short* pA1 = pA0 + 4096;

  f32x4 acc[4][4] = {};

  for (int t = 0; t < KB; t += 2) {
    // ---- even: MFMA(buf0, Bc); prefetch Bn(t+1); build buf1 for t+1 ----
    {
      Bn[0] = *(const uint4*)(Bf + bo0);
      Bn[1] = *(const uint4*)(Bf + bo1);
      Bn[2] = *(const uint4*)(Bf + bo2);
      Bn[3] = *(const uint4*)(Bf + bo3);
      bo0 += 1024; bo1 += 1024; bo2 += 1024; bo3 += 1024;
      const int kb = iprow[2 * (t + 1)] & 15;
      sA[prev1] = 0;
      prev1 = 4096 + slotbase + (((kb & 8) << 4) | (kb & 7));
      sA[prev1] = 0x3F80;
      bf16x8 af[4];
#pragma unroll
      for (int i = 0; i < 4; ++i) af[i] = *(const bf16x8*)(pA0 + i * 512);
#pragma unroll
      for (int i = 0; i < 4; ++i)
#pragma unroll
        for (int j = 0; j < 4; ++j)
          acc[i][j] = __builtin_amdgcn_mfma_f32_16x16x32_bf16(
              af[i], *(const bf16x8*)&Bc[j], acc[i][j], 0, 0, 0);
      __syncthreads();
    }
    // ---- odd: MFMA(buf1, Bn); prefetch Bc(t+2); build buf0 for t+2 ----
    {
      // t+2==KB on the last iter: B read runs 4KB past lutF (into the idx
      // region, allocated) and the build uses sIdx pad garbage masked to
      // 4 bits -> stays in own slots; both are dead after the final MFMA.
      Bc[0] = *(const uint4*)(Bf + bo0);
      Bc[1] = *(const uint4*)(Bf + bo1);
      Bc[2] = *(const uint4*)(Bf + bo2);
      Bc[3] = *(const uint4*)(Bf + bo3);
      bo0 += 1024; bo1 += 1024; bo2 += 1024; bo3 += 1024;
      const int kb = iprow[2 * (t + 2) < 256 ? 2 * (t + 2) : 254] & 15;
      sA[prev0] = 0;
      prev0 = slotbase + (((kb & 8) << 4) | (kb & 7));
      sA[prev0] = 0x3F80;
      bf16x8 af[4];
#pragma unroll
      for (int i = 0; i < 4; ++i) af[i] = *(const bf16x8*)(pA1 + i * 512);
#pragma unroll
      for (int i = 0; i < 4; ++i)
#pragma unroll
        for (int j = 0; j < 4; ++j)
          acc[i][j] = __builtin_amdgcn_mfma_f32_16x16x32_bf16(
              af[i], *(const bf16x8*)&Bn[j], acc[i][j], 0, 0, 0);
      __syncthreads();
    }
  }

  // epilogue: D layout col=lane&15, row=(lane>>4)*4+r  [m89-verified]
  const int col = lane & 15;
  const int rb = (lane >> 4) * 4;
  float bj[4];
#pragma unroll
  for (int j = 0; j < 4; ++j) bj[j] = bias[n0 + wn + j * 16 + col];
#pragma unroll
  for (int i = 0; i < 4; ++i) {
    const int gm = m0 + wm + i * 16 + rb;
#pragma unroll
    for (int j = 0; j < 4; ++j) {
      const int gn = n0 + wn + j * 16 + col;
      float* op = out + (size_t)gm * OUT_DIM + gn;
#pragma unroll
      for (int r = 0; r < 4; ++r) op[(size_t)r * OUT_DIM] = acc[i][j][r] + bj[j];
    }
  }
}

// ---------------------------------------------------------------------------
extern "C" void kernel_launch(void* const* d_in, const int* in_sizes, int n_in,
                              void* d_out, int out_size, void* d_ws, size_t ws_size,
                              hipStream_t stream) {
  (void)in_sizes; (void)n_in; (void)out_size; (void)ws_size;
  const float* x      = (const float*)d_in[0];
  const float* weight = (const float*)d_in[1];
  const float* cents  = (const float*)d_in[2];
  const float* bias   = (const float*)d_in[3];
  // d_in[4] = vec_len (16), hardcoded

  char* lutF = (char*)d_ws;                                              // 16.8MB
  unsigned char* idx = (unsigned char*)d_ws + (size_t)OUT_DIM * CK * 2;  // 512KB
  float* out = (float*)d_out;

  k_argmin_idx<<<dim3(N_TOK / 16, 2), 256, 0, stream>>>(x, cents, idx);
  k_lut<<<dim3(OUT_DIM / 64, NCB / 8), 256, 0, stream>>>(weight, cents, lutF);
  k_gemm<<<dim3(N_TOK / 128, OUT_DIM / 128), 256, 0, stream>>>(idx, lutF, bias, out);
}